// Round 1
// baseline (1769.609 us; speedup 1.0000x reference)
//
#include <hip/hip_runtime.h>
#include <cmath>

#define NN 20000   // nodes
#define NE 60000   // edges
#define NS 3000    // subgraphs
#define NG 128     // graphs
#define HIDN 128   // hidden dim of edge-attr MLP

__device__ __forceinline__ float eluf(float v) { return v > 0.f ? v : expm1f(v); }

// ---------------- slice x[:, :16] -> xi ----------------
__global__ void k_slice(const float* __restrict__ x, float* __restrict__ xi) {
    int idx = blockIdx.x * 256 + threadIdx.x;
    if (idx >= NN * 16) return;
    int n = idx >> 4, i = idx & 15;
    xi[idx] = x[n * 24 + i];
}

// ---------------- h = relu(ea @ w1 + b1)  (E x 128) ----------------
__global__ void k_h(const float* __restrict__ ea, const float* __restrict__ w1,
                    const float* __restrict__ b1, float* __restrict__ h) {
    int idx = blockIdx.x * 256 + threadIdx.x;
    if (idx >= NE * HIDN) return;
    int e = idx >> 7, j = idx & 127;
    float s = b1[j];
#pragma unroll
    for (int d = 0; d < 5; ++d) s = fmaf(ea[e * 5 + d], w1[d * HIDN + j], s);
    h[idx] = fmaxf(s, 0.f);
}

// ---------------- out = xi @ root + bias  (initializes the agg buffer) ----------------
template <int MI, int MO>
__global__ void k_root(const float* __restrict__ xi, const float* __restrict__ root,
                       const float* __restrict__ bias, float* __restrict__ out) {
    int idx = blockIdx.x * 256 + threadIdx.x;
    if (idx >= NN * MO) return;
    int n = idx / MO, o = idx % MO;
    float s = bias[o];
#pragma unroll
    for (int i = 0; i < MI; ++i) s = fmaf(xi[n * MI + i], root[i * MO + o], s);
    out[idx] = s;
}

// ---------------- fused edge kernel ----------------
// msg[e,o] = sum_{k,i} (h[e,k]*xi[src[e],i]) * w2[(k*MI+i)*MO+o] + sum_i xi[src[e],i]*b2[i*MO+o]
// atomically accumulated into out[dst[e]*MO+o].
// Block: 256 threads; per-thread tile = 4 edges x 8 outputs.
template <int MI, int MO>
__global__ __launch_bounds__(256, 2) void k_edge(
    const float* __restrict__ xi, const float* __restrict__ h,
    const float* __restrict__ w2, const float* __restrict__ b2,
    const int* __restrict__ src, const int* __restrict__ dst,
    float* __restrict__ out) {
    constexpr int OG = MO / 8;      // o-groups (threads along o)
    constexpr int EG = 256 / OG;    // e-groups
    constexpr int TE = EG * 4;      // edges per block
    constexpr int KK = 128 / MI;    // k values per K-chunk (chunk = KK*MI = 128 K rows)
    constexpr int NCH = HIDN / KK;  // number of K-chunks

    __shared__ float xs_lds[TE][MI + 1];
    __shared__ float h_lds[TE][KK + 1];
    __shared__ __align__(16) float w2_lds[128 * MO];

    const int t = threadIdx.x;
    const int to = t % OG;
    const int te = t / OG;
    const int eb = blockIdx.x * TE;
    const int ob = to * 8;

    // stage x[src] rows for this block's edges
    for (int idx = t; idx < TE * MI; idx += 256) {
        int el = idx / MI, i = idx % MI;
        int e = eb + el;
        xs_lds[el][i] = (e < NE) ? xi[src[e] * MI + i] : 0.f;
    }

    float acc[4][8];
#pragma unroll
    for (int j = 0; j < 4; ++j)
#pragma unroll
        for (int o = 0; o < 8; ++o) acc[j][o] = 0.f;

    for (int c = 0; c < NCH; ++c) {
        __syncthreads();
        // stage 128 x MO chunk of w2 (contiguous rows)
        const float* w2s = w2 + c * 128 * MO;
        for (int idx = t * 4; idx < 128 * MO; idx += 256 * 4)
            *reinterpret_cast<float4*>(&w2_lds[idx]) =
                *reinterpret_cast<const float4*>(&w2s[idx]);
        // stage h chunk: KK values per edge
        for (int idx = t; idx < TE * KK; idx += 256) {
            int el = idx / KK, kk = idx % KK;
            int e = eb + el;
            h_lds[el][kk] = (e < NE) ? h[e * HIDN + c * KK + kk] : 0.f;
        }
        __syncthreads();
#pragma unroll
        for (int kk = 0; kk < KK; ++kk) {
            float hreg[4];
#pragma unroll
            for (int j = 0; j < 4; ++j) hreg[j] = h_lds[te * 4 + j][kk];
#pragma unroll 4
            for (int i = 0; i < MI; ++i) {
                const float4 b0 = *reinterpret_cast<const float4*>(&w2_lds[(kk * MI + i) * MO + ob]);
                const float4 b1 = *reinterpret_cast<const float4*>(&w2_lds[(kk * MI + i) * MO + ob + 4]);
#pragma unroll
                for (int j = 0; j < 4; ++j) {
                    float a = hreg[j] * xs_lds[te * 4 + j][i];
                    acc[j][0] = fmaf(a, b0.x, acc[j][0]);
                    acc[j][1] = fmaf(a, b0.y, acc[j][1]);
                    acc[j][2] = fmaf(a, b0.z, acc[j][2]);
                    acc[j][3] = fmaf(a, b0.w, acc[j][3]);
                    acc[j][4] = fmaf(a, b1.x, acc[j][4]);
                    acc[j][5] = fmaf(a, b1.y, acc[j][5]);
                    acc[j][6] = fmaf(a, b1.z, acc[j][6]);
                    acc[j][7] = fmaf(a, b1.w, acc[j][7]);
                }
            }
        }
    }

    // b2 bias contribution: msg += xs @ B,  B[i][o] = b2[i*MO+o]
#pragma unroll 4
    for (int i = 0; i < MI; ++i) {
        const float4 b0 = *reinterpret_cast<const float4*>(&b2[i * MO + ob]);
        const float4 b1 = *reinterpret_cast<const float4*>(&b2[i * MO + ob + 4]);
#pragma unroll
        for (int j = 0; j < 4; ++j) {
            float a = xs_lds[te * 4 + j][i];
            acc[j][0] = fmaf(a, b0.x, acc[j][0]);
            acc[j][1] = fmaf(a, b0.y, acc[j][1]);
            acc[j][2] = fmaf(a, b0.z, acc[j][2]);
            acc[j][3] = fmaf(a, b0.w, acc[j][3]);
            acc[j][4] = fmaf(a, b1.x, acc[j][4]);
            acc[j][5] = fmaf(a, b1.y, acc[j][5]);
            acc[j][6] = fmaf(a, b1.z, acc[j][6]);
            acc[j][7] = fmaf(a, b1.w, acc[j][7]);
        }
    }

    // scatter to destination nodes
#pragma unroll
    for (int j = 0; j < 4; ++j) {
        int e = eb + te * 4 + j;
        if (e < NE) {
            int d = dst[e];
#pragma unroll
            for (int o = 0; o < 8; ++o)
                atomicAdd(&out[d * MO + ob + o], acc[j][o]);
        }
    }
}

// ---------------- ELU in place ----------------
__global__ void k_elu(float* __restrict__ a, int n) {
    int i = blockIdx.x * 256 + threadIdx.x;
    if (i < n) a[i] = eluf(a[i]);
}

// ---------------- pool nodes -> subgraphs (sum + count) ----------------
__global__ void k_pool_s(const float* __restrict__ xi, const float* __restrict__ x,
                         const int* __restrict__ n2s, float* __restrict__ xs_sum,
                         float* __restrict__ cs) {
    int idx = blockIdx.x * 256 + threadIdx.x;
    if (idx >= NN * 72) return;
    int n = idx / 72, j = idx % 72;
    float v = (j < 64) ? xi[n * 64 + j] : x[n * 24 + 16 + (j - 64)];
    int s = n2s[n];
    atomicAdd(&xs_sum[s * 72 + j], v);
    if (j == 0) atomicAdd(&cs[s], 1.f);
}

// ---------------- pool subgraphs -> graphs (mean of means) ----------------
__global__ void k_pool_g(const float* __restrict__ xs_sum, const float* __restrict__ cs,
                         const int* __restrict__ s2g, float* __restrict__ xg_sum,
                         float* __restrict__ cg) {
    int idx = blockIdx.x * 256 + threadIdx.x;
    if (idx >= NS * 72) return;
    int s = idx / 72, j = idx % 72;
    float v = xs_sum[s * 72 + j] / fmaxf(cs[s], 1.f);
    int g = s2g[s];
    atomicAdd(&xg_sum[g * 72 + j], v);
    if (j == 0) atomicAdd(&cg[g], 1.f);
}

// ---------------- final MLP: 72 -> 36 -> 18 -> 1 ----------------
__global__ void k_fc(const float* __restrict__ xg_sum, const float* __restrict__ cg,
                     const float* __restrict__ w1, const float* __restrict__ b1,
                     const float* __restrict__ w2, const float* __restrict__ b2,
                     const float* __restrict__ w3, const float* __restrict__ b3,
                     float* __restrict__ out) {
    int g = threadIdx.x;
    if (g >= NG) return;
    float inv = 1.f / fmaxf(cg[g], 1.f);
    float v[72];
#pragma unroll
    for (int j = 0; j < 72; ++j) v[j] = xg_sum[g * 72 + j] * inv;
    float h1[36];
#pragma unroll
    for (int o = 0; o < 36; ++o) {
        float s = b1[o];
#pragma unroll
        for (int i = 0; i < 72; ++i) s = fmaf(v[i], w1[i * 36 + o], s);
        h1[o] = eluf(s);
    }
    float h2[18];
#pragma unroll
    for (int o = 0; o < 18; ++o) {
        float s = b2[o];
#pragma unroll
        for (int i = 0; i < 36; ++i) s = fmaf(h1[i], w2[i * 18 + o], s);
        h2[o] = eluf(s);
    }
    float s = b3[0];
#pragma unroll
    for (int i = 0; i < 18; ++i) s = fmaf(h2[i], w3[i], s);
    out[g] = s;
}

// ---------------- launcher ----------------
extern "C" void kernel_launch(void* const* d_in, const int* in_sizes, int n_in,
                              void* d_out, int out_size, void* d_ws, size_t ws_size,
                              hipStream_t stream) {
    const float* x   = (const float*)d_in[0];
    const int*   ei  = (const int*)d_in[1];
    const float* ea  = (const float*)d_in[2];
    const int*   n2s = (const int*)d_in[3];
    const int*   s2g = (const int*)d_in[4];
    const int* src = ei;
    const int* dst = ei + NE;

    const float* cw1[3]   = {(const float*)d_in[5],  (const float*)d_in[11], (const float*)d_in[17]};
    const float* cb1[3]   = {(const float*)d_in[6],  (const float*)d_in[12], (const float*)d_in[18]};
    const float* cw2[3]   = {(const float*)d_in[7],  (const float*)d_in[13], (const float*)d_in[19]};
    const float* cb2[3]   = {(const float*)d_in[8],  (const float*)d_in[14], (const float*)d_in[20]};
    const float* croot[3] = {(const float*)d_in[9],  (const float*)d_in[15], (const float*)d_in[21]};
    const float* cbias[3] = {(const float*)d_in[10], (const float*)d_in[16], (const float*)d_in[22]};
    const float* fc1w = (const float*)d_in[23];
    const float* fc1b = (const float*)d_in[24];
    const float* fc2w = (const float*)d_in[25];
    const float* fc2b = (const float*)d_in[26];
    const float* fc3w = (const float*)d_in[27];
    const float* fc3b = (const float*)d_in[28];

    float* ws = (float*)d_ws;
    float* h      = ws;                       // E*128
    float* xiA    = h + NE * HIDN;            // N*64
    float* xiB    = xiA + NN * 64;            // N*64
    float* xs_sum = xiB + NN * 64;            // S*72
    float* cs     = xs_sum + NS * 72;         // S
    float* xg_sum = cs + NS;                  // G*72
    float* cg     = xg_sum + NG * 72;         // G

    // zero the pooling accumulators (contiguous region)
    hipMemsetAsync(xs_sum, 0, (size_t)(NS * 72 + NS + NG * 72 + NG) * sizeof(float), stream);

    k_slice<<<(NN * 16 + 255) / 256, 256, 0, stream>>>(x, xiA);

    // ---- layer 0: MI=16, MO=32, in xiA -> out xiB ----
    k_h<<<(NE * HIDN + 255) / 256, 256, 0, stream>>>(ea, cw1[0], cb1[0], h);
    k_root<16, 32><<<(NN * 32 + 255) / 256, 256, 0, stream>>>(xiA, croot[0], cbias[0], xiB);
    {
        constexpr int TE = (256 / (32 / 8)) * 4;  // 256
        k_edge<16, 32><<<(NE + TE - 1) / TE, 256, 0, stream>>>(xiA, h, cw2[0], cb2[0], src, dst, xiB);
    }
    k_elu<<<(NN * 32 + 255) / 256, 256, 0, stream>>>(xiB, NN * 32);

    // ---- layer 1: MI=32, MO=64, in xiB -> out xiA ----
    k_h<<<(NE * HIDN + 255) / 256, 256, 0, stream>>>(ea, cw1[1], cb1[1], h);
    k_root<32, 64><<<(NN * 64 + 255) / 256, 256, 0, stream>>>(xiB, croot[1], cbias[1], xiA);
    {
        constexpr int TE = (256 / (64 / 8)) * 4;  // 128
        k_edge<32, 64><<<(NE + TE - 1) / TE, 256, 0, stream>>>(xiB, h, cw2[1], cb2[1], src, dst, xiA);
    }
    k_elu<<<(NN * 64 + 255) / 256, 256, 0, stream>>>(xiA, NN * 64);

    // ---- layer 2: MI=64, MO=64, in xiA -> out xiB ----
    k_h<<<(NE * HIDN + 255) / 256, 256, 0, stream>>>(ea, cw1[2], cb1[2], h);
    k_root<64, 64><<<(NN * 64 + 255) / 256, 256, 0, stream>>>(xiA, croot[2], cbias[2], xiB);
    {
        constexpr int TE = (256 / (64 / 8)) * 4;  // 128
        k_edge<64, 64><<<(NE + TE - 1) / TE, 256, 0, stream>>>(xiA, h, cw2[2], cb2[2], src, dst, xiB);
    }
    k_elu<<<(NN * 64 + 255) / 256, 256, 0, stream>>>(xiB, NN * 64);

    // ---- pooling + MLP ----
    k_pool_s<<<(NN * 72 + 255) / 256, 256, 0, stream>>>(xiB, x, n2s, xs_sum, cs);
    k_pool_g<<<(NS * 72 + 255) / 256, 256, 0, stream>>>(xs_sum, cs, s2g, xg_sum, cg);
    k_fc<<<1, 128, 0, stream>>>(xg_sum, cg, fc1w, fc1b, fc2w, fc2b, fc3w, fc3b, (float*)d_out);
}

// Round 2
// 607.076 us; speedup vs baseline: 2.9150x; 2.9150x over previous
//
#include <hip/hip_runtime.h>
#include <hip/hip_bf16.h>
#include <cmath>

#define NN 20000   // nodes
#define NE 60000   // edges
#define NS 3000    // subgraphs
#define NG 128     // graphs
#define HIDN 128   // hidden dim of edge-attr MLP

typedef float f32x16 __attribute__((ext_vector_type(16)));
typedef __bf16 bf16x8 __attribute__((ext_vector_type(8)));

__device__ __forceinline__ float eluf(float v) { return v > 0.f ? v : expm1f(v); }

// ---------------- slice x[:, :16] -> xi ----------------
__global__ void k_slice(const float* __restrict__ x, float* __restrict__ xi) {
    int idx = blockIdx.x * 256 + threadIdx.x;
    if (idx >= NN * 16) return;
    int n = idx >> 4, i = idx & 15;
    xi[idx] = x[n * 24 + i];
}

// ---------------- h = relu(ea @ w1 + b1)  (E x 128, bf16) ----------------
__global__ void k_h(const float* __restrict__ ea, const float* __restrict__ w1,
                    const float* __restrict__ b1, __bf16* __restrict__ hb) {
    int idx = blockIdx.x * 256 + threadIdx.x;
    if (idx >= NE * HIDN) return;
    int e = idx >> 7, j = idx & 127;
    float s = b1[j];
#pragma unroll
    for (int d = 0; d < 5; ++d) s = fmaf(ea[e * 5 + d], w1[d * HIDN + j], s);
    hb[idx] = (__bf16)fmaxf(s, 0.f);
}

// ---------------- w2t[o][kg] = bf16( kg<128*MI ? w2[kg*MO+o] : b2[(kg-128MI)*MO+o] ) ----------------
template <int MI, int MO>
__global__ void k_w2t(const float* __restrict__ w2, const float* __restrict__ b2,
                      __bf16* __restrict__ w2t) {
    constexpr int KP = 129 * MI;
    constexpr int KF = 128 * MI;
    int idx = blockIdx.x * 256 + threadIdx.x;
    if (idx >= MO * KP) return;
    int o = idx / KP, kg = idx % KP;
    float v = (kg < KF) ? w2[(size_t)kg * MO + o] : b2[(kg - KF) * MO + o];
    w2t[idx] = (__bf16)v;
}

// ---------------- out = xi @ root + bias  (initializes the agg buffer) ----------------
template <int MI, int MO>
__global__ void k_root(const float* __restrict__ xi, const float* __restrict__ root,
                       const float* __restrict__ bias, float* __restrict__ out) {
    int idx = blockIdx.x * 256 + threadIdx.x;
    if (idx >= NN * MO) return;
    int n = idx / MO, o = idx % MO;
    float s = bias[o];
#pragma unroll
    for (int i = 0; i < MI; ++i) s = fmaf(xi[n * MI + i], root[i * MO + o], s);
    out[idx] = s;
}

// ---------------- MFMA edge kernel ----------------
// GEMM: msg[e,o] = sum_kg G[e,kg]*w2t[o][kg],  G[e, k*MI+i] = hfac(e,k)*xi[src[e],i]
// hfac = h[e,k] for k<128, 1.0 for k==128 (the folded b2 term).
// Wave = 64 edges (2 M-tiles of 32) x full MO. K split across blockIdx.y.
template <int MI, int MO, int KSPLIT>
__global__ __launch_bounds__(256, 2) void k_edge_mfma(
    const float* __restrict__ xi, const __bf16* __restrict__ hb,
    const __bf16* __restrict__ w2t,
    const int* __restrict__ src, const int* __restrict__ dst,
    float* __restrict__ out) {
    constexpr int PH = MI / 16;      // K-steps per k value
    constexpr int KP = 129 * MI;     // w2t row length
    constexpr int NT = MO / 32;      // N tiles

    const int lane = threadIdx.x & 63;
    const int w    = threadIdx.x >> 6;
    const int lo5  = lane & 31;
    const int hi   = lane >> 5;
    const int e0   = blockIdx.x * 256 + w * 64;
    if (e0 >= NE) return;

    const int kb = (129 * (int)blockIdx.y) / KSPLIT;
    const int ke = (129 * ((int)blockIdx.y + 1)) / KSPLIT;

    int r0 = e0 + lo5, r1 = e0 + 32 + lo5;
    const int rc0 = (r0 < NE) ? r0 : 0;
    const int rc1 = (r1 < NE) ? r1 : 0;
    const int s0 = src[rc0];
    const int s1 = src[rc1];

    // gather this lane's x fragment subset into registers
    float xr0[PH][8], xr1[PH][8];
    {
        const float* xb0 = xi + (size_t)s0 * MI + hi * 8;
        const float* xb1 = xi + (size_t)s1 * MI + hi * 8;
#pragma unroll
        for (int p = 0; p < PH; ++p) {
            float4 a = *reinterpret_cast<const float4*>(xb0 + p * 16);
            float4 b = *reinterpret_cast<const float4*>(xb0 + p * 16 + 4);
            xr0[p][0] = a.x; xr0[p][1] = a.y; xr0[p][2] = a.z; xr0[p][3] = a.w;
            xr0[p][4] = b.x; xr0[p][5] = b.y; xr0[p][6] = b.z; xr0[p][7] = b.w;
            float4 c = *reinterpret_cast<const float4*>(xb1 + p * 16);
            float4 d = *reinterpret_cast<const float4*>(xb1 + p * 16 + 4);
            xr1[p][0] = c.x; xr1[p][1] = c.y; xr1[p][2] = c.z; xr1[p][3] = c.w;
            xr1[p][4] = d.x; xr1[p][5] = d.y; xr1[p][6] = d.z; xr1[p][7] = d.w;
        }
    }

    f32x16 acc[2][NT];
#pragma unroll
    for (int m = 0; m < 2; ++m)
#pragma unroll
        for (int n = 0; n < NT; ++n)
#pragma unroll
            for (int i = 0; i < 16; ++i) acc[m][n][i] = 0.f;

    const __bf16* bcol[NT];
#pragma unroll
    for (int n = 0; n < NT; ++n)
        bcol[n] = w2t + (size_t)(n * 32 + lo5) * KP + hi * 8;

#pragma unroll 2
    for (int k = kb; k < ke; ++k) {
        const float hv0 = (k < 128) ? (float)hb[(size_t)rc0 * HIDN + k] : 1.0f;
        const float hv1 = (k < 128) ? (float)hb[(size_t)rc1 * HIDN + k] : 1.0f;
#pragma unroll
        for (int p = 0; p < PH; ++p) {
            bf16x8 af0, af1;
#pragma unroll
            for (int j = 0; j < 8; ++j) {
                af0[j] = (__bf16)(hv0 * xr0[p][j]);
                af1[j] = (__bf16)(hv1 * xr1[p][j]);
            }
#pragma unroll
            for (int n = 0; n < NT; ++n) {
                const bf16x8 bv = *reinterpret_cast<const bf16x8*>(bcol[n] + k * MI + p * 16);
                acc[0][n] = __builtin_amdgcn_mfma_f32_32x32x16_bf16(af0, bv, acc[0][n], 0, 0, 0);
                acc[1][n] = __builtin_amdgcn_mfma_f32_32x32x16_bf16(af1, bv, acc[1][n], 0, 0, 0);
            }
        }
    }

    // epilogue: C layout col = lane&31, row = (reg&3) + 8*(reg>>2) + 4*(lane>>5)
#pragma unroll
    for (int m = 0; m < 2; ++m) {
        const int ebase = e0 + m * 32;
#pragma unroll
        for (int q = 0; q < 4; ++q) {
#pragma unroll
            for (int a = 0; a < 4; ++a) {
                const int e = ebase + 4 * hi + 8 * q + a;
                if (e < NE) {
                    const int d = dst[e];
#pragma unroll
                    for (int n = 0; n < NT; ++n) {
                        const float v = (m == 0) ? acc[0][n][4 * q + a] : acc[1][n][4 * q + a];
                        atomicAdd(&out[(size_t)d * MO + n * 32 + lo5], v);
                    }
                }
            }
        }
    }
}

// ---------------- ELU in place ----------------
__global__ void k_elu(float* __restrict__ a, int n) {
    int i = blockIdx.x * 256 + threadIdx.x;
    if (i < n) a[i] = eluf(a[i]);
}

// ---------------- pool nodes -> subgraphs (sum + count) ----------------
__global__ void k_pool_s(const float* __restrict__ xi, const float* __restrict__ x,
                         const int* __restrict__ n2s, float* __restrict__ xs_sum,
                         float* __restrict__ cs) {
    int idx = blockIdx.x * 256 + threadIdx.x;
    if (idx >= NN * 72) return;
    int n = idx / 72, j = idx % 72;
    float v = (j < 64) ? xi[n * 64 + j] : x[n * 24 + 16 + (j - 64)];
    int s = n2s[n];
    atomicAdd(&xs_sum[s * 72 + j], v);
    if (j == 0) atomicAdd(&cs[s], 1.f);
}

// ---------------- pool subgraphs -> graphs (mean of means) ----------------
__global__ void k_pool_g(const float* __restrict__ xs_sum, const float* __restrict__ cs,
                         const int* __restrict__ s2g, float* __restrict__ xg_sum,
                         float* __restrict__ cg) {
    int idx = blockIdx.x * 256 + threadIdx.x;
    if (idx >= NS * 72) return;
    int s = idx / 72, j = idx % 72;
    float v = xs_sum[s * 72 + j] / fmaxf(cs[s], 1.f);
    int g = s2g[s];
    atomicAdd(&xg_sum[g * 72 + j], v);
    if (j == 0) atomicAdd(&cg[g], 1.f);
}

// ---------------- final MLP: 72 -> 36 -> 18 -> 1 ----------------
__global__ void k_fc(const float* __restrict__ xg_sum, const float* __restrict__ cg,
                     const float* __restrict__ w1, const float* __restrict__ b1,
                     const float* __restrict__ w2, const float* __restrict__ b2,
                     const float* __restrict__ w3, const float* __restrict__ b3,
                     float* __restrict__ out) {
    int g = threadIdx.x;
    if (g >= NG) return;
    float inv = 1.f / fmaxf(cg[g], 1.f);
    float v[72];
#pragma unroll
    for (int j = 0; j < 72; ++j) v[j] = xg_sum[g * 72 + j] * inv;
    float h1[36];
#pragma unroll
    for (int o = 0; o < 36; ++o) {
        float s = b1[o];
#pragma unroll
        for (int i = 0; i < 72; ++i) s = fmaf(v[i], w1[i * 36 + o], s);
        h1[o] = eluf(s);
    }
    float h2[18];
#pragma unroll
    for (int o = 0; o < 18; ++o) {
        float s = b2[o];
#pragma unroll
        for (int i = 0; i < 36; ++i) s = fmaf(h1[i], w2[i * 18 + o], s);
        h2[o] = eluf(s);
    }
    float s = b3[0];
#pragma unroll
    for (int i = 0; i < 18; ++i) s = fmaf(h2[i], w3[i], s);
    out[g] = s;
}

// ---------------- launcher ----------------
extern "C" void kernel_launch(void* const* d_in, const int* in_sizes, int n_in,
                              void* d_out, int out_size, void* d_ws, size_t ws_size,
                              hipStream_t stream) {
    const float* x   = (const float*)d_in[0];
    const int*   ei  = (const int*)d_in[1];
    const float* ea  = (const float*)d_in[2];
    const int*   n2s = (const int*)d_in[3];
    const int*   s2g = (const int*)d_in[4];
    const int* src = ei;
    const int* dst = ei + NE;

    const float* cw1[3]   = {(const float*)d_in[5],  (const float*)d_in[11], (const float*)d_in[17]};
    const float* cb1[3]   = {(const float*)d_in[6],  (const float*)d_in[12], (const float*)d_in[18]};
    const float* cw2[3]   = {(const float*)d_in[7],  (const float*)d_in[13], (const float*)d_in[19]};
    const float* cb2[3]   = {(const float*)d_in[8],  (const float*)d_in[14], (const float*)d_in[20]};
    const float* croot[3] = {(const float*)d_in[9],  (const float*)d_in[15], (const float*)d_in[21]};
    const float* cbias[3] = {(const float*)d_in[10], (const float*)d_in[16], (const float*)d_in[22]};
    const float* fc1w = (const float*)d_in[23];
    const float* fc1b = (const float*)d_in[24];
    const float* fc2w = (const float*)d_in[25];
    const float* fc2b = (const float*)d_in[26];
    const float* fc3w = (const float*)d_in[27];
    const float* fc3b = (const float*)d_in[28];

    // ---- workspace layout (bytes) ----
    char* W = (char*)d_ws;
    __bf16* hb    = (__bf16*)(W);                   // NE*128*2      = 15,360,000
    float*  xiA   = (float*)(W + 15360000);         // NN*64*4       =  5,120,000
    float*  xiB   = (float*)(W + 20480000);         // NN*64*4       =  5,120,000
    float*  xs_sum= (float*)(W + 25600000);         // NS*72*4       =    864,000
    float*  cs    = (float*)(W + 26464000);         // NS*4          =     12,000
    float*  xg_sum= (float*)(W + 26476000);         // NG*72*4       =     36,864
    float*  cg    = (float*)(W + 26512864);         // NG*4          =        512
    __bf16* w2t0  = (__bf16*)(W + 26513376);        // 32*2064*2     =    132,096
    __bf16* w2t1  = (__bf16*)(W + 26645472);        // 64*4128*2     =    528,384
    __bf16* w2t2  = (__bf16*)(W + 27173856);        // 64*8256*2     =  1,056,768
    // total 28,230,624 bytes

    // zero the pooling accumulators (contiguous region)
    hipMemsetAsync(xs_sum, 0, (size_t)(NS * 72 + NS) * 4 + (size_t)(NG * 72 + NG) * 4, stream);

    // prep: transposed bf16 W2 (with b2 folded as k==128)
    k_w2t<16, 32><<<(32 * 129 * 16 + 255) / 256, 256, 0, stream>>>(cw2[0], cb2[0], w2t0);
    k_w2t<32, 64><<<(64 * 129 * 32 + 255) / 256, 256, 0, stream>>>(cw2[1], cb2[1], w2t1);
    k_w2t<64, 64><<<(64 * 129 * 64 + 255) / 256, 256, 0, stream>>>(cw2[2], cb2[2], w2t2);

    k_slice<<<(NN * 16 + 255) / 256, 256, 0, stream>>>(x, xiA);

    const int EB = (NE + 255) / 256;

    // ---- layer 0: MI=16, MO=32, xiA -> xiB ----
    k_h<<<(NE * HIDN + 255) / 256, 256, 0, stream>>>(ea, cw1[0], cb1[0], hb);
    k_root<16, 32><<<(NN * 32 + 255) / 256, 256, 0, stream>>>(xiA, croot[0], cbias[0], xiB);
    k_edge_mfma<16, 32, 2><<<dim3(EB, 2), 256, 0, stream>>>(xiA, hb, w2t0, src, dst, xiB);
    k_elu<<<(NN * 32 + 255) / 256, 256, 0, stream>>>(xiB, NN * 32);

    // ---- layer 1: MI=32, MO=64, xiB -> xiA ----
    k_h<<<(NE * HIDN + 255) / 256, 256, 0, stream>>>(ea, cw1[1], cb1[1], hb);
    k_root<32, 64><<<(NN * 64 + 255) / 256, 256, 0, stream>>>(xiB, croot[1], cbias[1], xiA);
    k_edge_mfma<32, 64, 2><<<dim3(EB, 2), 256, 0, stream>>>(xiB, hb, w2t1, src, dst, xiA);
    k_elu<<<(NN * 64 + 255) / 256, 256, 0, stream>>>(xiA, NN * 64);

    // ---- layer 2: MI=64, MO=64, xiA -> xiB ----
    k_h<<<(NE * HIDN + 255) / 256, 256, 0, stream>>>(ea, cw1[2], cb1[2], hb);
    k_root<64, 64><<<(NN * 64 + 255) / 256, 256, 0, stream>>>(xiA, croot[2], cbias[2], xiB);
    k_edge_mfma<64, 64, 2><<<dim3(EB, 2), 256, 0, stream>>>(xiA, hb, w2t2, src, dst, xiB);
    k_elu<<<(NN * 64 + 255) / 256, 256, 0, stream>>>(xiB, NN * 64);

    // ---- pooling + MLP ----
    k_pool_s<<<(NN * 72 + 255) / 256, 256, 0, stream>>>(xiB, x, n2s, xs_sum, cs);
    k_pool_g<<<(NS * 72 + 255) / 256, 256, 0, stream>>>(xs_sum, cs, s2g, xg_sum, cg);
    k_fc<<<1, 128, 0, stream>>>(xg_sum, cg, fc1w, fc1b, fc2w, fc2b, fc3w, fc3b, (float*)d_out);
}

// Round 3
// 526.587 us; speedup vs baseline: 3.3605x; 1.1528x over previous
//
#include <hip/hip_runtime.h>
#include <hip/hip_bf16.h>
#include <cmath>

#define NN 20000   // nodes
#define NE 60000   // edges
#define NS 3000    // subgraphs
#define NG 128     // graphs
#define HIDN 128   // hidden dim of edge-attr MLP

typedef float f32x16 __attribute__((ext_vector_type(16)));
typedef __bf16 bf16x8 __attribute__((ext_vector_type(8)));

__device__ __forceinline__ float eluf(float v) { return v > 0.f ? v : expm1f(v); }

// ---------------- h = relu(ea @ w1 + b1)  (E x 128, bf16) ----------------
__global__ void k_h(const float* __restrict__ ea, const float* __restrict__ w1,
                    const float* __restrict__ b1, __bf16* __restrict__ hb) {
    int idx = blockIdx.x * 256 + threadIdx.x;
    if (idx >= NE * HIDN) return;
    int e = idx >> 7, j = idx & 127;
    float s = b1[j];
#pragma unroll
    for (int d = 0; d < 5; ++d) s = fmaf(ea[e * 5 + d], w1[d * HIDN + j], s);
    hb[idx] = (__bf16)fmaxf(s, 0.f);
}

// ---------------- w2t[o][kg] = bf16( kg<128*MI ? w2[kg*MO+o] : b2[(kg-128MI)*MO+o] ) ----------------
template <int MI, int MO>
__global__ void k_w2t(const float* __restrict__ w2, const float* __restrict__ b2,
                      __bf16* __restrict__ w2t) {
    constexpr int KP = 129 * MI;
    constexpr int KF = 128 * MI;
    int idx = blockIdx.x * 256 + threadIdx.x;
    if (idx >= MO * KP) return;
    int o = idx / KP, kg = idx % KP;
    float v = (kg < KF) ? w2[(size_t)kg * MO + o] : b2[(kg - KF) * MO + o];
    w2t[idx] = (__bf16)v;
}

// ---------------- out = xi @ root + bias  (initializes the agg buffer) ----------------
// XS = row stride of xi (layer 0 reads x directly with stride 24)
template <int MI, int MO, int XS>
__global__ void k_root(const float* __restrict__ xi, const float* __restrict__ root,
                       const float* __restrict__ bias, float* __restrict__ out) {
    int idx = blockIdx.x * 256 + threadIdx.x;
    if (idx >= NN * MO) return;
    int n = idx / MO, o = idx % MO;
    float s = bias[o];
#pragma unroll
    for (int i = 0; i < MI; ++i) s = fmaf(xi[(size_t)n * XS + i], root[i * MO + o], s);
    out[idx] = s;
}

// ---------------- MFMA edge kernel ----------------
// GEMM: msg[e,o] = sum_kg G[e,kg]*w2t[o][kg],  G[e, k*MI+i] = hfac(e,k)*xi[src[e],i]
// hfac = h[e,k] for k<128, 1.0 for k==128 (the folded b2 term, last y-block only).
// Wave = 64 edges (2 M-tiles of 32) x full MO. K split across blockIdx.y (KCH=128/KSPLIT each).
template <int MI, int MO, int XS, int KSPLIT>
__global__ __launch_bounds__(256, 2) void k_edge_mfma(
    const float* __restrict__ xi, const __bf16* __restrict__ hb,
    const __bf16* __restrict__ w2t,
    const int* __restrict__ src, const int* __restrict__ dst,
    float* __restrict__ out) {
    constexpr int PH = MI / 16;        // K-steps per k value
    constexpr int KP = 129 * MI;       // w2t row length
    constexpr int NT = MO / 32;        // N tiles
    constexpr int KCH = 128 / KSPLIT;  // k values per y-block (main loop)

    const int lane = threadIdx.x & 63;
    const int w    = threadIdx.x >> 6;
    const int lo5  = lane & 31;
    const int hi   = lane >> 5;
    const int e0   = blockIdx.x * 256 + w * 64;
    if (e0 >= NE) return;

    const int kb = KCH * (int)blockIdx.y;

    int r0 = e0 + lo5, r1 = e0 + 32 + lo5;
    const int rc0 = (r0 < NE) ? r0 : 0;
    const int rc1 = (r1 < NE) ? r1 : 0;
    const int s0 = src[rc0];
    const int s1 = src[rc1];

    // gather this lane's x fragment subset into registers
    float xr0[PH][8], xr1[PH][8];
    {
        const float* xb0 = xi + (size_t)s0 * XS + hi * 8;
        const float* xb1 = xi + (size_t)s1 * XS + hi * 8;
#pragma unroll
        for (int p = 0; p < PH; ++p) {
            float4 a = *reinterpret_cast<const float4*>(xb0 + p * 16);
            float4 b = *reinterpret_cast<const float4*>(xb0 + p * 16 + 4);
            xr0[p][0] = a.x; xr0[p][1] = a.y; xr0[p][2] = a.z; xr0[p][3] = a.w;
            xr0[p][4] = b.x; xr0[p][5] = b.y; xr0[p][6] = b.z; xr0[p][7] = b.w;
            float4 c = *reinterpret_cast<const float4*>(xb1 + p * 16);
            float4 d = *reinterpret_cast<const float4*>(xb1 + p * 16 + 4);
            xr1[p][0] = c.x; xr1[p][1] = c.y; xr1[p][2] = c.z; xr1[p][3] = c.w;
            xr1[p][4] = d.x; xr1[p][5] = d.y; xr1[p][6] = d.z; xr1[p][7] = d.w;
        }
    }

    f32x16 acc[2][NT];
#pragma unroll
    for (int m = 0; m < 2; ++m)
#pragma unroll
        for (int n = 0; n < NT; ++n)
#pragma unroll
            for (int i = 0; i < 16; ++i) acc[m][n][i] = 0.f;

    // B column pointers, pre-offset to this y-block's k range
    const __bf16* bcol[NT];
#pragma unroll
    for (int n = 0; n < NT; ++n)
        bcol[n] = w2t + (size_t)(n * 32 + lo5) * KP + hi * 8 + (size_t)kb * MI;

    const __bf16* hrow0 = hb + (size_t)rc0 * HIDN + kb;
    const __bf16* hrow1 = hb + (size_t)rc1 * HIDN + kb;

    for (int kc = 0; kc < KCH; kc += 8) {
        const bf16x8 h80 = *reinterpret_cast<const bf16x8*>(hrow0 + kc);
        const bf16x8 h81 = *reinterpret_cast<const bf16x8*>(hrow1 + kc);
#pragma unroll
        for (int kk = 0; kk < 8; ++kk) {
            const int k = kc + kk;
            const float hv0 = (float)h80[kk];
            const float hv1 = (float)h81[kk];
#pragma unroll
            for (int p = 0; p < PH; ++p) {
                bf16x8 af0, af1;
#pragma unroll
                for (int j = 0; j < 8; ++j) {
                    af0[j] = (__bf16)(hv0 * xr0[p][j]);
                    af1[j] = (__bf16)(hv1 * xr1[p][j]);
                }
#pragma unroll
                for (int n = 0; n < NT; ++n) {
                    const bf16x8 bv = *reinterpret_cast<const bf16x8*>(bcol[n] + k * MI + p * 16);
                    acc[0][n] = __builtin_amdgcn_mfma_f32_32x32x16_bf16(af0, bv, acc[0][n], 0, 0, 0);
                    acc[1][n] = __builtin_amdgcn_mfma_f32_32x32x16_bf16(af1, bv, acc[1][n], 0, 0, 0);
                }
            }
        }
    }

    // k == 128 tail (folded b2 term, hfac = 1) — only the last y-block
    if (blockIdx.y == KSPLIT - 1) {
#pragma unroll
        for (int p = 0; p < PH; ++p) {
            bf16x8 af0, af1;
#pragma unroll
            for (int j = 0; j < 8; ++j) {
                af0[j] = (__bf16)xr0[p][j];
                af1[j] = (__bf16)xr1[p][j];
            }
#pragma unroll
            for (int n = 0; n < NT; ++n) {
                const bf16x8 bv = *reinterpret_cast<const bf16x8*>(bcol[n] + (128 - kb) * MI + p * 16);
                acc[0][n] = __builtin_amdgcn_mfma_f32_32x32x16_bf16(af0, bv, acc[0][n], 0, 0, 0);
                acc[1][n] = __builtin_amdgcn_mfma_f32_32x32x16_bf16(af1, bv, acc[1][n], 0, 0, 0);
            }
        }
    }

    // epilogue: C layout col = lane&31, row = (reg&3) + 8*(reg>>2) + 4*(lane>>5)
#pragma unroll
    for (int m = 0; m < 2; ++m) {
        const int ebase = e0 + m * 32;
#pragma unroll
        for (int q = 0; q < 4; ++q) {
#pragma unroll
            for (int a = 0; a < 4; ++a) {
                const int e = ebase + 4 * hi + 8 * q + a;
                if (e < NE) {
                    const int d = dst[e];
#pragma unroll
                    for (int n = 0; n < NT; ++n) {
                        const float v = (m == 0) ? acc[0][n][4 * q + a] : acc[1][n][4 * q + a];
                        atomicAdd(&out[(size_t)d * MO + n * 32 + lo5], v);
                    }
                }
            }
        }
    }
}

// ---------------- ELU in place ----------------
__global__ void k_elu(float* __restrict__ a, int n) {
    int i = blockIdx.x * 256 + threadIdx.x;
    if (i < n) a[i] = eluf(a[i]);
}

// ---------------- pool nodes -> subgraphs (sum + count) ----------------
__global__ void k_pool_s(const float* __restrict__ xi, const float* __restrict__ x,
                         const int* __restrict__ n2s, float* __restrict__ xs_sum,
                         float* __restrict__ cs) {
    int idx = blockIdx.x * 256 + threadIdx.x;
    if (idx >= NN * 72) return;
    int n = idx / 72, j = idx % 72;
    float v = (j < 64) ? xi[n * 64 + j] : x[n * 24 + 16 + (j - 64)];
    int s = n2s[n];
    atomicAdd(&xs_sum[s * 72 + j], v);
    if (j == 0) atomicAdd(&cs[s], 1.f);
}

// ---------------- pool subgraphs -> graphs (mean of means) ----------------
__global__ void k_pool_g(const float* __restrict__ xs_sum, const float* __restrict__ cs,
                         const int* __restrict__ s2g, float* __restrict__ xg_sum,
                         float* __restrict__ cg) {
    int idx = blockIdx.x * 256 + threadIdx.x;
    if (idx >= NS * 72) return;
    int s = idx / 72, j = idx % 72;
    float v = xs_sum[s * 72 + j] / fmaxf(cs[s], 1.f);
    int g = s2g[s];
    atomicAdd(&xg_sum[g * 72 + j], v);
    if (j == 0) atomicAdd(&cg[g], 1.f);
}

// ---------------- final MLP: 72 -> 36 -> 18 -> 1 ----------------
__global__ void k_fc(const float* __restrict__ xg_sum, const float* __restrict__ cg,
                     const float* __restrict__ w1, const float* __restrict__ b1,
                     const float* __restrict__ w2, const float* __restrict__ b2,
                     const float* __restrict__ w3, const float* __restrict__ b3,
                     float* __restrict__ out) {
    int g = threadIdx.x;
    if (g >= NG) return;
    float inv = 1.f / fmaxf(cg[g], 1.f);
    float v[72];
#pragma unroll
    for (int j = 0; j < 72; ++j) v[j] = xg_sum[g * 72 + j] * inv;
    float h1[36];
#pragma unroll
    for (int o = 0; o < 36; ++o) {
        float s = b1[o];
#pragma unroll
        for (int i = 0; i < 72; ++i) s = fmaf(v[i], w1[i * 36 + o], s);
        h1[o] = eluf(s);
    }
    float h2[18];
#pragma unroll
    for (int o = 0; o < 18; ++o) {
        float s = b2[o];
#pragma unroll
        for (int i = 0; i < 36; ++i) s = fmaf(h1[i], w2[i * 18 + o], s);
        h2[o] = eluf(s);
    }
    float s = b3[0];
#pragma unroll
    for (int i = 0; i < 18; ++i) s = fmaf(h2[i], w3[i], s);
    out[g] = s;
}

// ---------------- launcher ----------------
extern "C" void kernel_launch(void* const* d_in, const int* in_sizes, int n_in,
                              void* d_out, int out_size, void* d_ws, size_t ws_size,
                              hipStream_t stream) {
    const float* x   = (const float*)d_in[0];
    const int*   ei  = (const int*)d_in[1];
    const float* ea  = (const float*)d_in[2];
    const int*   n2s = (const int*)d_in[3];
    const int*   s2g = (const int*)d_in[4];
    const int* src = ei;
    const int* dst = ei + NE;

    const float* cw1[3]   = {(const float*)d_in[5],  (const float*)d_in[11], (const float*)d_in[17]};
    const float* cb1[3]   = {(const float*)d_in[6],  (const float*)d_in[12], (const float*)d_in[18]};
    const float* cw2[3]   = {(const float*)d_in[7],  (const float*)d_in[13], (const float*)d_in[19]};
    const float* cb2[3]   = {(const float*)d_in[8],  (const float*)d_in[14], (const float*)d_in[20]};
    const float* croot[3] = {(const float*)d_in[9],  (const float*)d_in[15], (const float*)d_in[21]};
    const float* cbias[3] = {(const float*)d_in[10], (const float*)d_in[16], (const float*)d_in[22]};
    const float* fc1w = (const float*)d_in[23];
    const float* fc1b = (const float*)d_in[24];
    const float* fc2w = (const float*)d_in[25];
    const float* fc2b = (const float*)d_in[26];
    const float* fc3w = (const float*)d_in[27];
    const float* fc3b = (const float*)d_in[28];

    // ---- workspace layout (bytes) ----
    char* W = (char*)d_ws;
    __bf16* hb    = (__bf16*)(W);                   // NE*128*2      = 15,360,000
    float*  xiA   = (float*)(W + 15360000);         // NN*64*4       =  5,120,000
    float*  xiB   = (float*)(W + 20480000);         // NN*64*4       =  5,120,000
    float*  xs_sum= (float*)(W + 25600000);         // NS*72*4       =    864,000
    float*  cs    = (float*)(W + 26464000);         // NS*4          =     12,000
    float*  xg_sum= (float*)(W + 26476000);         // NG*72*4       =     36,864
    float*  cg    = (float*)(W + 26512864);         // NG*4          =        512
    __bf16* w2t0  = (__bf16*)(W + 26513376);        // 32*2064*2     =    132,096
    __bf16* w2t1  = (__bf16*)(W + 26645472);        // 64*4128*2     =    528,384
    __bf16* w2t2  = (__bf16*)(W + 27173856);        // 64*8256*2     =  1,056,768
    // total 28,230,624 bytes

    // zero the pooling accumulators (contiguous region)
    hipMemsetAsync(xs_sum, 0, (size_t)(NS * 72 + NS) * 4 + (size_t)(NG * 72 + NG) * 4, stream);

    // prep: transposed bf16 W2 (with b2 folded as k==128)
    k_w2t<16, 32><<<(32 * 129 * 16 + 255) / 256, 256, 0, stream>>>(cw2[0], cb2[0], w2t0);
    k_w2t<32, 64><<<(64 * 129 * 32 + 255) / 256, 256, 0, stream>>>(cw2[1], cb2[1], w2t1);
    k_w2t<64, 64><<<(64 * 129 * 64 + 255) / 256, 256, 0, stream>>>(cw2[2], cb2[2], w2t2);

    const int EB = (NE + 255) / 256;

    // ---- layer 0: MI=16, MO=32, x (stride 24) -> xiB ----
    k_h<<<(NE * HIDN + 255) / 256, 256, 0, stream>>>(ea, cw1[0], cb1[0], hb);
    k_root<16, 32, 24><<<(NN * 32 + 255) / 256, 256, 0, stream>>>(x, croot[0], cbias[0], xiB);
    k_edge_mfma<16, 32, 24, 4><<<dim3(EB, 4), 256, 0, stream>>>(x, hb, w2t0, src, dst, xiB);
    k_elu<<<(NN * 32 + 255) / 256, 256, 0, stream>>>(xiB, NN * 32);

    // ---- layer 1: MI=32, MO=64, xiB -> xiA ----
    k_h<<<(NE * HIDN + 255) / 256, 256, 0, stream>>>(ea, cw1[1], cb1[1], hb);
    k_root<32, 64, 32><<<(NN * 64 + 255) / 256, 256, 0, stream>>>(xiB, croot[1], cbias[1], xiA);
    k_edge_mfma<32, 64, 32, 4><<<dim3(EB, 4), 256, 0, stream>>>(xiB, hb, w2t1, src, dst, xiA);
    k_elu<<<(NN * 64 + 255) / 256, 256, 0, stream>>>(xiA, NN * 64);

    // ---- layer 2: MI=64, MO=64, xiA -> xiB ----
    k_h<<<(NE * HIDN + 255) / 256, 256, 0, stream>>>(ea, cw1[2], cb1[2], hb);
    k_root<64, 64, 64><<<(NN * 64 + 255) / 256, 256, 0, stream>>>(xiA, croot[2], cbias[2], xiB);
    k_edge_mfma<64, 64, 64, 4><<<dim3(EB, 4), 256, 0, stream>>>(xiA, hb, w2t2, src, dst, xiB);
    k_elu<<<(NN * 64 + 255) / 256, 256, 0, stream>>>(xiB, NN * 64);

    // ---- pooling + MLP ----
    k_pool_s<<<(NN * 72 + 255) / 256, 256, 0, stream>>>(xiB, x, n2s, xs_sum, cs);
    k_pool_g<<<(NS * 72 + 255) / 256, 256, 0, stream>>>(xs_sum, cs, s2g, xg_sum, cg);
    k_fc<<<1, 128, 0, stream>>>(xg_sum, cg, fc1w, fc1b, fc2w, fc2b, fc3w, fc3b, (float*)d_out);
}

// Round 4
// 414.338 us; speedup vs baseline: 4.2709x; 1.2709x over previous
//
#include <hip/hip_runtime.h>
#include <hip/hip_bf16.h>
#include <cmath>

#define NN 20000   // nodes
#define NE 60000   // edges
#define NS 3000    // subgraphs
#define NG 128     // graphs
#define HIDN 128   // hidden dim of edge-attr MLP

typedef float f32x16 __attribute__((ext_vector_type(16)));
typedef __bf16 bf16x8 __attribute__((ext_vector_type(8)));

__device__ __forceinline__ float eluf(float v) { return v > 0.f ? v : expm1f(v); }

// async global->LDS, 16B per lane; lptr must be wave-uniform (HW writes base + lane*16)
__device__ __forceinline__ void gload_lds16(const void* g, void* l) {
    __builtin_amdgcn_global_load_lds(
        (const __attribute__((address_space(1))) unsigned int*)g,
        (__attribute__((address_space(3))) unsigned int*)l, 16, 0, 0);
}

// ---------------- h = relu(ea @ w1 + b1)  (E x 128, bf16) ----------------
__global__ void k_h(const float* __restrict__ ea, const float* __restrict__ w1,
                    const float* __restrict__ b1, __bf16* __restrict__ hb) {
    int idx = blockIdx.x * 256 + threadIdx.x;
    if (idx >= NE * HIDN) return;
    int e = idx >> 7, j = idx & 127;
    float s = b1[j];
#pragma unroll
    for (int d = 0; d < 5; ++d) s = fmaf(ea[e * 5 + d], w1[d * HIDN + j], s);
    hb[idx] = (__bf16)fmaxf(s, 0.f);
}

// ---------------- w2t[o][kg] = bf16( kg<128*MI ? w2[kg*MO+o] : b2[(kg-128MI)*MO+o] ) ----------------
template <int MI, int MO>
__global__ void k_w2t(const float* __restrict__ w2, const float* __restrict__ b2,
                      __bf16* __restrict__ w2t) {
    constexpr int KP = 129 * MI;
    constexpr int KF = 128 * MI;
    int idx = blockIdx.x * 256 + threadIdx.x;
    if (idx >= MO * KP) return;
    int o = idx / KP, kg = idx % KP;
    float v = (kg < KF) ? w2[(size_t)kg * MO + o] : b2[(kg - KF) * MO + o];
    w2t[idx] = (__bf16)v;
}

// ---------------- out = xi @ root + bias  (initializes the agg buffer) ----------------
template <int MI, int MO, int XS>
__global__ void k_root(const float* __restrict__ xi, const float* __restrict__ root,
                       const float* __restrict__ bias, float* __restrict__ out) {
    int idx = blockIdx.x * 256 + threadIdx.x;
    if (idx >= NN * MO) return;
    int n = idx / MO, o = idx % MO;
    float s = bias[o];
#pragma unroll
    for (int i = 0; i < MI; ++i) s = fmaf(xi[(size_t)n * XS + i], root[i * MO + o], s);
    out[idx] = s;
}

// ---------------- MFMA edge kernel, LDS-staged B ----------------
// GEMM: msg[e,o] = sum_kg G[e,kg]*w2t[o][kg],  G[e, k*MI+i] = hfac(e,k)*xi[src[e],i]
// B staged in LDS via global_load_lds (double-buffered CH-k chunks), shared by all 4 waves.
// Wave = 64 edges (2 M-tiles of 32) x full MO. K split across blockIdx.y.
template <int MI, int MO, int XS, int KSPLIT, int CH>
__global__ __launch_bounds__(256, 2) void k_edge_mfma(
    const float* __restrict__ xi, const __bf16* __restrict__ hb,
    const __bf16* __restrict__ w2t,
    const int* __restrict__ src, const int* __restrict__ dst,
    float* __restrict__ out) {
    constexpr int PH  = MI / 16;        // K-steps per k value
    constexpr int KP  = 129 * MI;       // w2t row length
    constexpr int NT  = MO / 32;        // N tiles
    constexpr int KCH = 128 / KSPLIT;   // k values per y-block (main loop)
    constexpr int NCH = KCH / CH;       // chunks per y-block
    constexpr int ITEMS = CH * PH * NT; // 1KB items per chunk
    constexpr int NBUF = (NCH > 1) ? 2 : 1;

    __shared__ __align__(16) __bf16 sb[NBUF][ITEMS * 512];

    const int lane = threadIdx.x & 63;
    const int w    = threadIdx.x >> 6;
    const int lo5  = lane & 31;
    const int hi   = lane >> 5;
    const int e0   = blockIdx.x * 256 + w * 64;   // may exceed NE for tail waves: no early return (barriers)

    const int kb = KCH * (int)blockIdx.y;

    int r0 = e0 + lo5, r1 = e0 + 32 + lo5;
    const int rc0 = (r0 < NE) ? r0 : 0;
    const int rc1 = (r1 < NE) ? r1 : 0;
    const int s0 = src[rc0];
    const int s1 = src[rc1];

    // gather this lane's x fragment subset into registers
    float xr0[PH][8], xr1[PH][8];
    {
        const float* xb0 = xi + (size_t)s0 * XS + hi * 8;
        const float* xb1 = xi + (size_t)s1 * XS + hi * 8;
#pragma unroll
        for (int p = 0; p < PH; ++p) {
            float4 a = *reinterpret_cast<const float4*>(xb0 + p * 16);
            float4 b = *reinterpret_cast<const float4*>(xb0 + p * 16 + 4);
            xr0[p][0] = a.x; xr0[p][1] = a.y; xr0[p][2] = a.z; xr0[p][3] = a.w;
            xr0[p][4] = b.x; xr0[p][5] = b.y; xr0[p][6] = b.z; xr0[p][7] = b.w;
            float4 c = *reinterpret_cast<const float4*>(xb1 + p * 16);
            float4 d = *reinterpret_cast<const float4*>(xb1 + p * 16 + 4);
            xr1[p][0] = c.x; xr1[p][1] = c.y; xr1[p][2] = c.z; xr1[p][3] = c.w;
            xr1[p][4] = d.x; xr1[p][5] = d.y; xr1[p][6] = d.z; xr1[p][7] = d.w;
        }
    }

    f32x16 acc[2][NT];
#pragma unroll
    for (int m = 0; m < 2; ++m)
#pragma unroll
        for (int n = 0; n < NT; ++n)
#pragma unroll
            for (int i = 0; i < 16; ++i) acc[m][n][i] = 0.f;

    const __bf16* hrow0 = hb + (size_t)rc0 * HIDN + kb;
    const __bf16* hrow1 = hb + (size_t)rc1 * HIDN + kb;

    // stage chunk starting at k-offset kc into buffer buf: wave w stages items w, w+4, ...
    auto stage = [&](int buf, int kc) {
#pragma unroll
        for (int j = w; j < ITEMS; j += 4) {
            const int n  = j % NT;
            const int kp = j / NT;
            const int p  = kp % PH;
            const int kk = kp / PH;
            const __bf16* g = w2t + (size_t)(n * 32 + lo5) * KP
                              + (size_t)(kb + kc + kk) * MI + p * 16 + hi * 8;
            gload_lds16(g, &sb[buf][j * 512]);
        }
    };

    stage(0, 0);
    for (int c = 0; c < NCH; ++c) {
        __syncthreads();                      // drains chunk-c staging (vmcnt) for all waves
        if (c + 1 < NCH) stage((c + 1) & 1, (c + 1) * CH);
        const int cb = c & 1;
        const int kc = c * CH;
        __bf16 h0a[CH], h1a[CH];
#pragma unroll
        for (int i = 0; i < CH; ++i) { h0a[i] = hrow0[kc + i]; h1a[i] = hrow1[kc + i]; }
#pragma unroll
        for (int kk = 0; kk < CH; ++kk) {
            const float hv0 = (float)h0a[kk];
            const float hv1 = (float)h1a[kk];
#pragma unroll
            for (int p = 0; p < PH; ++p) {
                bf16x8 af0, af1;
#pragma unroll
                for (int j = 0; j < 8; ++j) {
                    af0[j] = (__bf16)(hv0 * xr0[p][j]);
                    af1[j] = (__bf16)(hv1 * xr1[p][j]);
                }
#pragma unroll
                for (int n = 0; n < NT; ++n) {
                    const bf16x8 bv = *reinterpret_cast<const bf16x8*>(
                        &sb[cb][((kk * PH + p) * NT + n) * 512 + lane * 8]);
                    acc[0][n] = __builtin_amdgcn_mfma_f32_32x32x16_bf16(af0, bv, acc[0][n], 0, 0, 0);
                    acc[1][n] = __builtin_amdgcn_mfma_f32_32x32x16_bf16(af1, bv, acc[1][n], 0, 0, 0);
                }
            }
        }
    }

    // k == 128 tail (folded b2 term, hfac = 1) — only the last y-block, direct global B
    if (blockIdx.y == KSPLIT - 1) {
#pragma unroll
        for (int p = 0; p < PH; ++p) {
            bf16x8 af0, af1;
#pragma unroll
            for (int j = 0; j < 8; ++j) {
                af0[j] = (__bf16)xr0[p][j];
                af1[j] = (__bf16)xr1[p][j];
            }
#pragma unroll
            for (int n = 0; n < NT; ++n) {
                const bf16x8 bv = *reinterpret_cast<const bf16x8*>(
                    w2t + (size_t)(n * 32 + lo5) * KP + (size_t)128 * MI + p * 16 + hi * 8);
                acc[0][n] = __builtin_amdgcn_mfma_f32_32x32x16_bf16(af0, bv, acc[0][n], 0, 0, 0);
                acc[1][n] = __builtin_amdgcn_mfma_f32_32x32x16_bf16(af1, bv, acc[1][n], 0, 0, 0);
            }
        }
    }

    // epilogue: C layout col = lane&31, row = (reg&3) + 8*(reg>>2) + 4*(lane>>5)
#pragma unroll
    for (int m = 0; m < 2; ++m) {
        const int ebase = e0 + m * 32;
#pragma unroll
        for (int q = 0; q < 4; ++q) {
#pragma unroll
            for (int a = 0; a < 4; ++a) {
                const int e = ebase + 4 * hi + 8 * q + a;
                if (e < NE) {
                    const int d = dst[e];
#pragma unroll
                    for (int n = 0; n < NT; ++n) {
                        const float v = (m == 0) ? acc[0][n][4 * q + a] : acc[1][n][4 * q + a];
                        atomicAdd(&out[(size_t)d * MO + n * 32 + lo5], v);
                    }
                }
            }
        }
    }
}

// ---------------- ELU in place ----------------
__global__ void k_elu(float* __restrict__ a, int n) {
    int i = blockIdx.x * 256 + threadIdx.x;
    if (i < n) a[i] = eluf(a[i]);
}

// ---------------- pool nodes -> subgraphs (sum + count) ----------------
__global__ void k_pool_s(const float* __restrict__ xi, const float* __restrict__ x,
                         const int* __restrict__ n2s, float* __restrict__ xs_sum,
                         float* __restrict__ cs) {
    int idx = blockIdx.x * 256 + threadIdx.x;
    if (idx >= NN * 72) return;
    int n = idx / 72, j = idx % 72;
    float v = (j < 64) ? xi[n * 64 + j] : x[n * 24 + 16 + (j - 64)];
    int s = n2s[n];
    atomicAdd(&xs_sum[s * 72 + j], v);
    if (j == 0) atomicAdd(&cs[s], 1.f);
}

// ---------------- pool subgraphs -> graphs (mean of means) ----------------
__global__ void k_pool_g(const float* __restrict__ xs_sum, const float* __restrict__ cs,
                         const int* __restrict__ s2g, float* __restrict__ xg_sum,
                         float* __restrict__ cg) {
    int idx = blockIdx.x * 256 + threadIdx.x;
    if (idx >= NS * 72) return;
    int s = idx / 72, j = idx % 72;
    float v = xs_sum[s * 72 + j] / fmaxf(cs[s], 1.f);
    int g = s2g[s];
    atomicAdd(&xg_sum[g * 72 + j], v);
    if (j == 0) atomicAdd(&cg[g], 1.f);
}

// ---------------- final MLP: 72 -> 36 -> 18 -> 1 ----------------
__global__ void k_fc(const float* __restrict__ xg_sum, const float* __restrict__ cg,
                     const float* __restrict__ w1, const float* __restrict__ b1,
                     const float* __restrict__ w2, const float* __restrict__ b2,
                     const float* __restrict__ w3, const float* __restrict__ b3,
                     float* __restrict__ out) {
    int g = threadIdx.x;
    if (g >= NG) return;
    float inv = 1.f / fmaxf(cg[g], 1.f);
    float v[72];
#pragma unroll
    for (int j = 0; j < 72; ++j) v[j] = xg_sum[g * 72 + j] * inv;
    float h1[36];
#pragma unroll
    for (int o = 0; o < 36; ++o) {
        float s = b1[o];
#pragma unroll
        for (int i = 0; i < 72; ++i) s = fmaf(v[i], w1[i * 36 + o], s);
        h1[o] = eluf(s);
    }
    float h2[18];
#pragma unroll
    for (int o = 0; o < 18; ++o) {
        float s = b2[o];
#pragma unroll
        for (int i = 0; i < 36; ++i) s = fmaf(h1[i], w2[i * 18 + o], s);
        h2[o] = eluf(s);
    }
    float s = b3[0];
#pragma unroll
    for (int i = 0; i < 18; ++i) s = fmaf(h2[i], w3[i], s);
    out[g] = s;
}

// ---------------- launcher ----------------
extern "C" void kernel_launch(void* const* d_in, const int* in_sizes, int n_in,
                              void* d_out, int out_size, void* d_ws, size_t ws_size,
                              hipStream_t stream) {
    const float* x   = (const float*)d_in[0];
    const int*   ei  = (const int*)d_in[1];
    const float* ea  = (const float*)d_in[2];
    const int*   n2s = (const int*)d_in[3];
    const int*   s2g = (const int*)d_in[4];
    const int* src = ei;
    const int* dst = ei + NE;

    const float* cw1[3]   = {(const float*)d_in[5],  (const float*)d_in[11], (const float*)d_in[17]};
    const float* cb1[3]   = {(const float*)d_in[6],  (const float*)d_in[12], (const float*)d_in[18]};
    const float* cw2[3]   = {(const float*)d_in[7],  (const float*)d_in[13], (const float*)d_in[19]};
    const float* cb2[3]   = {(const float*)d_in[8],  (const float*)d_in[14], (const float*)d_in[20]};
    const float* croot[3] = {(const float*)d_in[9],  (const float*)d_in[15], (const float*)d_in[21]};
    const float* cbias[3] = {(const float*)d_in[10], (const float*)d_in[16], (const float*)d_in[22]};
    const float* fc1w = (const float*)d_in[23];
    const float* fc1b = (const float*)d_in[24];
    const float* fc2w = (const float*)d_in[25];
    const float* fc2b = (const float*)d_in[26];
    const float* fc3w = (const float*)d_in[27];
    const float* fc3b = (const float*)d_in[28];

    // ---- workspace layout (bytes) ----
    char* W = (char*)d_ws;
    __bf16* hb    = (__bf16*)(W);                   // NE*128*2      = 15,360,000
    float*  xiA   = (float*)(W + 15360000);         // NN*64*4       =  5,120,000
    float*  xiB   = (float*)(W + 20480000);         // NN*64*4       =  5,120,000
    float*  xs_sum= (float*)(W + 25600000);         // NS*72*4       =    864,000
    float*  cs    = (float*)(W + 26464000);         // NS*4          =     12,000
    float*  xg_sum= (float*)(W + 26476000);         // NG*72*4       =     36,864
    float*  cg    = (float*)(W + 26512864);         // NG*4          =        512
    __bf16* w2t0  = (__bf16*)(W + 26513376);        // 32*2064*2     =    132,096
    __bf16* w2t1  = (__bf16*)(W + 26645472);        // 64*4128*2     =    528,384
    __bf16* w2t2  = (__bf16*)(W + 27173856);        // 64*8256*2     =  1,056,768
    // total 28,230,624 bytes

    // zero the pooling accumulators (contiguous region)
    hipMemsetAsync(xs_sum, 0, (size_t)(NS * 72 + NS) * 4 + (size_t)(NG * 72 + NG) * 4, stream);

    // prep: transposed bf16 W2 (with b2 folded as k==128)
    k_w2t<16, 32><<<(32 * 129 * 16 + 255) / 256, 256, 0, stream>>>(cw2[0], cb2[0], w2t0);
    k_w2t<32, 64><<<(64 * 129 * 32 + 255) / 256, 256, 0, stream>>>(cw2[1], cb2[1], w2t1);
    k_w2t<64, 64><<<(64 * 129 * 64 + 255) / 256, 256, 0, stream>>>(cw2[2], cb2[2], w2t2);

    const int EB = (NE + 255) / 256;

    // ---- layer 0: MI=16, MO=32, x (stride 24) -> xiB ----
    k_h<<<(NE * HIDN + 255) / 256, 256, 0, stream>>>(ea, cw1[0], cb1[0], hb);
    k_root<16, 32, 24><<<(NN * 32 + 255) / 256, 256, 0, stream>>>(x, croot[0], cbias[0], xiB);
    k_edge_mfma<16, 32, 24, 4, 32><<<dim3(EB, 4), 256, 0, stream>>>(x, hb, w2t0, src, dst, xiB);
    k_elu<<<(NN * 32 + 255) / 256, 256, 0, stream>>>(xiB, NN * 32);

    // ---- layer 1: MI=32, MO=64, xiB -> xiA ----
    k_h<<<(NE * HIDN + 255) / 256, 256, 0, stream>>>(ea, cw1[1], cb1[1], hb);
    k_root<32, 64, 32><<<(NN * 64 + 255) / 256, 256, 0, stream>>>(xiB, croot[1], cbias[1], xiA);
    k_edge_mfma<32, 64, 32, 4, 8><<<dim3(EB, 4), 256, 0, stream>>>(xiB, hb, w2t1, src, dst, xiA);
    k_elu<<<(NN * 64 + 255) / 256, 256, 0, stream>>>(xiA, NN * 64);

    // ---- layer 2: MI=64, MO=64, xiA -> xiB ----
    k_h<<<(NE * HIDN + 255) / 256, 256, 0, stream>>>(ea, cw1[2], cb1[2], hb);
    k_root<64, 64, 64><<<(NN * 64 + 255) / 256, 256, 0, stream>>>(xiA, croot[2], cbias[2], xiB);
    k_edge_mfma<64, 64, 64, 4, 4><<<dim3(EB, 4), 256, 0, stream>>>(xiA, hb, w2t2, src, dst, xiB);
    k_elu<<<(NN * 64 + 255) / 256, 256, 0, stream>>>(xiB, NN * 64);

    // ---- pooling + MLP ----
    k_pool_s<<<(NN * 72 + 255) / 256, 256, 0, stream>>>(xiB, x, n2s, xs_sum, cs);
    k_pool_g<<<(NS * 72 + 255) / 256, 256, 0, stream>>>(xs_sum, cs, s2g, xg_sum, cg);
    k_fc<<<1, 128, 0, stream>>>(xg_sum, cg, fc1w, fc1b, fc2w, fc2b, fc3w, fc3b, (float*)d_out);
}